// Round 15
// baseline (85.111 us; speedup 1.0000x reference)
//
#include <hip/hip_runtime.h>
#include <math.h>

// FFF sparse tree forward. B=16384, D_IN=D_OUT=768, DEPTH=11, n_nodes=4095.
//
// R13 post-mortem: request count is NOT the cost (78->54 req: null). Model:
// ~50us constant = phase-1 serial walk, concurrency-capped (~5-6 effective
// chains/CU vs 32 resident) by per-CU L1 miss-fill capacity on gathered
// lines. R14: merge w2 accumulation INTO the walk so each wave has 3 extra
// independent requests + ~30 VALU ops inside every W1-gather stall, at zero
// occupancy cost (no acts[] array; acc replaces it; peak regs ~60 <= 64).
// Issue order per level: w2[node_k] FIRST, then W1[node_{k+1}]; in-order
// vmcnt -> w2 consumable while W1 still in flight.
//
// bf16 staged weights (R12); routing sign exact vs f64 reference via
// |p|<0.03 fallback to f64 dot on original f32 w1s (R5-proven).
// Tripwires: VGPR <= 72, WRITE_SIZE(main) == 49152 KB.

#define FFF_LVLS 12        // depth+1
#define FFF_D 768
#define FFF_ROWF4 192      // float4 per 768-f32 row
#define FFF_NODES 4095
#define WAVES_PER_BLOCK 16

typedef unsigned short u16x8 __attribute__((ext_vector_type(8)));
typedef unsigned short u16x4 __attribute__((ext_vector_type(4)));

__device__ __forceinline__ float gelu_exact(float v) {
    return 0.5f * v * (1.0f + erff(v * 0.70710678118654752440f));
}

__device__ __forceinline__ unsigned short f32_to_bf16_rne(float f) {
    unsigned int u = __builtin_bit_cast(unsigned int, f);
    u += 0x7FFFu + ((u >> 16) & 1u);
    return (unsigned short)(u >> 16);
}
__device__ __forceinline__ float bf(unsigned short h) {
    return __builtin_bit_cast(float, (unsigned int)h << 16);
}

template <int CTRL>
__device__ __forceinline__ float dpp_shr_add(float v) {
    const int t = __builtin_amdgcn_update_dpp(
        0, __builtin_bit_cast(int, v), CTRL, 0xf, 0xf, true);
    return v + __builtin_bit_cast(float, t);
}

// Wave64 sum, pure VALU; lanes 15/31/47/63 hold row totals after 4 steps.
__device__ __forceinline__ float wave_allsum_f32(float v) {
    v = dpp_shr_add<0x111>(v);   // row_shr:1
    v = dpp_shr_add<0x112>(v);   // row_shr:2
    v = dpp_shr_add<0x114>(v);   // row_shr:4
    v = dpp_shr_add<0x118>(v);   // row_shr:8
    const int i15 = __builtin_amdgcn_readlane(__builtin_bit_cast(int, v), 15);
    const int i31 = __builtin_amdgcn_readlane(__builtin_bit_cast(int, v), 31);
    const int i47 = __builtin_amdgcn_readlane(__builtin_bit_cast(int, v), 47);
    const int i63 = __builtin_amdgcn_readlane(__builtin_bit_cast(int, v), 63);
    return (__builtin_bit_cast(float, i15) + __builtin_bit_cast(float, i31))
         + (__builtin_bit_cast(float, i47) + __builtin_bit_cast(float, i63));
}

// f32 -> bf16 staging of W1 and w2 (runs each call; deterministic).
__global__ void __launch_bounds__(1024) fff_convert_kernel(
    const float4* __restrict__ w1, const float4* __restrict__ w2,
    ushort4* __restrict__ o1, ushort4* __restrict__ o2, int nf4)
{
    int i = blockIdx.x * blockDim.x + threadIdx.x;
    if (i < nf4) {
        const float4 v = w1[i];
        ushort4 h;
        h.x = f32_to_bf16_rne(v.x); h.y = f32_to_bf16_rne(v.y);
        h.z = f32_to_bf16_rne(v.z); h.w = f32_to_bf16_rne(v.w);
        o1[i] = h;
    } else if (i < 2 * nf4) {
        const int j = i - nf4;
        const float4 v = w2[j];
        ushort4 h;
        h.x = f32_to_bf16_rne(v.x); h.y = f32_to_bf16_rne(v.y);
        h.z = f32_to_bf16_rne(v.z); h.w = f32_to_bf16_rne(v.w);
        o2[j] = h;
    }
}

__global__ void __launch_bounds__(1024) fff_sparse_kernel_bf16(
    const float* __restrict__ x,
    const float* __restrict__ w1s,              // f32, sign-fallback only
    const unsigned short* __restrict__ w1b,     // bf16, 768 per row
    const unsigned short* __restrict__ w2b,
    float* __restrict__ out,
    int B)
{
    const int wave = threadIdx.x >> 6;
    const int lane = threadIdx.x & 63;
    const int b = blockIdx.x * WAVES_PER_BLOCK + wave;
    if (b >= B) return;

    const float4* __restrict__ xf4 = (const float4*)(x) + (size_t)b * FFF_ROWF4;

    // Packed lane<->dim map: lane l owns dims 8l..8l+7 and 512+4l..515+4l.
    const float4 xA0 = xf4[2 * lane];
    const float4 xA1 = xf4[2 * lane + 1];
    const float4 xB  = xf4[128 + lane];

    float4 accA0 = make_float4(0.f, 0.f, 0.f, 0.f);
    float4 accA1 = make_float4(0.f, 0.f, 0.f, 0.f);
    float4 accB  = make_float4(0.f, 0.f, 0.f, 0.f);

    int node = 0;

    // Prefetch root W1 row.
    u16x8 wA = ((const u16x8*)w1b)[lane];
    u16x4 wB = ((const u16x4*)(w1b + 512))[lane];

#pragma unroll
    for (int lvl = 0; lvl < FFF_LVLS; ++lvl) {
        // Dot on the already-fetched W1 row (two chains).
        float q0 = xA0.x * bf(wA[0]);
        float q1 = xA0.y * bf(wA[1]);
        q0 = fmaf(xA0.z, bf(wA[2]), q0);
        q1 = fmaf(xA0.w, bf(wA[3]), q1);
        q0 = fmaf(xA1.x, bf(wA[4]), q0);
        q1 = fmaf(xA1.y, bf(wA[5]), q1);
        q0 = fmaf(xA1.z, bf(wA[6]), q0);
        q1 = fmaf(xA1.w, bf(wA[7]), q1);
        q0 = fmaf(xB.x,  bf(wB[0]), q0);
        q1 = fmaf(xB.y,  bf(wB[1]), q1);
        q0 = fmaf(xB.z,  bf(wB[2]), q0);
        q1 = fmaf(xB.w,  bf(wB[3]), q1);

        float p = wave_allsum_f32(q0 + q1);   // wave-uniform

        // Sign-ambiguity fallback (~4% of levels): f64 dot on original f32.
        if (__builtin_expect(fabsf(p) < 0.03f, 0)) {
            const float4* __restrict__ rf = (const float4*)w1s
                                          + (size_t)node * FFF_ROWF4;
            const float4 a0 = rf[2 * lane];
            const float4 a1 = rf[2 * lane + 1];
            const float4 a2 = rf[128 + lane];
            double d0 = (double)xA0.x * (double)a0.x;
            double d1 = (double)xA0.y * (double)a0.y;
            d0 += (double)xA0.z * (double)a0.z;
            d1 += (double)xA0.w * (double)a0.w;
            d0 += (double)xA1.x * (double)a1.x;
            d1 += (double)xA1.y * (double)a1.y;
            d0 += (double)xA1.z * (double)a1.z;
            d1 += (double)xA1.w * (double)a1.w;
            d0 += (double)xB.x  * (double)a2.x;
            d1 += (double)xB.y  * (double)a2.y;
            d0 += (double)xB.z  * (double)a2.z;
            d1 += (double)xB.w  * (double)a2.w;
            double pd = d0 + d1;
#pragma unroll
            for (int m = 32; m > 0; m >>= 1) pd += __shfl_xor(pd, m, 64);
            p = (float)pd;
        }

        const int s = (p >= 0.0f) ? 1 : 0;
        const int cur = node;               // node for w2 of this level
        node = 2 * node + 1 + s;

        // Issue w2[cur] FIRST (consumed this level), then W1[next] (consumed
        // next level). In-order vmcnt: w2 usable while W1 still in flight.
        const unsigned short* __restrict__ row2 = w2b + (size_t)cur * FFF_D;
        const u16x8 cA = ((const u16x8*)row2)[lane];
        const u16x4 cB = ((const u16x4*)(row2 + 512))[lane];

        if (lvl + 1 < FFF_LVLS) {
            const unsigned short* __restrict__ row1 = w1b + (size_t)node * FFF_D;
            wA = ((const u16x8*)row1)[lane];
            wB = ((const u16x4*)(row1 + 512))[lane];
        }

        // GELU (off-chain) + accumulate w2 — fills the W1 stall shadow.
        const float a = gelu_exact(p);
        accA0.x = fmaf(a, bf(cA[0]), accA0.x);
        accA0.y = fmaf(a, bf(cA[1]), accA0.y);
        accA0.z = fmaf(a, bf(cA[2]), accA0.z);
        accA0.w = fmaf(a, bf(cA[3]), accA0.w);
        accA1.x = fmaf(a, bf(cA[4]), accA1.x);
        accA1.y = fmaf(a, bf(cA[5]), accA1.y);
        accA1.z = fmaf(a, bf(cA[6]), accA1.z);
        accA1.w = fmaf(a, bf(cA[7]), accA1.w);
        accB.x  = fmaf(a, bf(cB[0]), accB.x);
        accB.y  = fmaf(a, bf(cB[1]), accB.y);
        accB.z  = fmaf(a, bf(cB[2]), accB.z);
        accB.w  = fmaf(a, bf(cB[3]), accB.w);
    }

    float4* __restrict__ of4 = (float4*)(out) + (size_t)b * FFF_ROWF4;
    of4[2 * lane]     = accA0;
    of4[2 * lane + 1] = accA1;
    of4[128 + lane]   = accB;
}

// Fallback (ws too small): proven R11 all-f32 kernel.
__global__ void __launch_bounds__(1024) fff_sparse_kernel_f32(
    const float* __restrict__ x,
    const float* __restrict__ w1s,
    const float* __restrict__ w2s,
    float* __restrict__ out,
    int B)
{
    const int wave = threadIdx.x >> 6;
    const int lane = threadIdx.x & 63;
    const int b = blockIdx.x * WAVES_PER_BLOCK + wave;
    if (b >= B) return;

    const float4* __restrict__ xf4  = (const float4*)x;
    const float4* __restrict__ w1f4 = (const float4*)w1s;
    const float4* __restrict__ w2f4 = (const float4*)w2s;

    const int xb = b * FFF_ROWF4 + lane;
    const float4 xv0 = xf4[xb];
    const float4 xv1 = xf4[xb + 64];
    const float4 xv2 = xf4[xb + 128];

    float acts[FFF_LVLS];
    int bits = 0;
    int node = 0;

#pragma unroll
    for (int lvl = 0; lvl < FFF_LVLS; ++lvl) {
        const int r = node * FFF_ROWF4 + lane;
        const float4 a0 = w1f4[r];
        const float4 a1 = w1f4[r + 64];
        const float4 a2 = w1f4[r + 128];
        float q0 = xv0.x * a0.x;
        float q1 = xv0.y * a0.y;
        q0 = fmaf(xv0.z, a0.z, q0);
        q1 = fmaf(xv0.w, a0.w, q1);
        q0 = fmaf(xv1.x, a1.x, q0);
        q1 = fmaf(xv1.y, a1.y, q1);
        q0 = fmaf(xv1.z, a1.z, q0);
        q1 = fmaf(xv1.w, a1.w, q1);
        q0 = fmaf(xv2.x, a2.x, q0);
        q1 = fmaf(xv2.y, a2.y, q1);
        q0 = fmaf(xv2.z, a2.z, q0);
        q1 = fmaf(xv2.w, a2.w, q1);
        float p = wave_allsum_f32(q0 + q1);
        if (__builtin_expect(fabsf(p) < 1e-4f, 0)) {
            double d0 = (double)xv0.x * (double)a0.x;
            double d1 = (double)xv0.y * (double)a0.y;
            d0 += (double)xv0.z * (double)a0.z;
            d1 += (double)xv0.w * (double)a0.w;
            d0 += (double)xv1.x * (double)a1.x;
            d1 += (double)xv1.y * (double)a1.y;
            d0 += (double)xv1.z * (double)a1.z;
            d1 += (double)xv1.w * (double)a1.w;
            d0 += (double)xv2.x * (double)a2.x;
            d1 += (double)xv2.y * (double)a2.y;
            d0 += (double)xv2.z * (double)a2.z;
            d1 += (double)xv2.w * (double)a2.w;
            double pd = d0 + d1;
#pragma unroll
            for (int m = 32; m > 0; m >>= 1) pd += __shfl_xor(pd, m, 64);
            p = (float)pd;
        }
        acts[lvl] = gelu_exact(p);
        const int s = (p >= 0.0f) ? 1 : 0;
        bits |= s << lvl;
        node = 2 * node + 1 + s;
    }

    float4 acc0 = make_float4(0.f, 0.f, 0.f, 0.f);
    float4 acc1 = make_float4(0.f, 0.f, 0.f, 0.f);
    float4 acc2 = make_float4(0.f, 0.f, 0.f, 0.f);
    node = 0;
#pragma unroll
    for (int lvl = 0; lvl < FFF_LVLS; ++lvl) {
        const int r = node * FFF_ROWF4 + lane;
        const float4 c0 = w2f4[r];
        const float4 c1 = w2f4[r + 64];
        const float4 c2 = w2f4[r + 128];
        const float a = acts[lvl];
        acc0.x = fmaf(a, c0.x, acc0.x); acc0.y = fmaf(a, c0.y, acc0.y);
        acc0.z = fmaf(a, c0.z, acc0.z); acc0.w = fmaf(a, c0.w, acc0.w);
        acc1.x = fmaf(a, c1.x, acc1.x); acc1.y = fmaf(a, c1.y, acc1.y);
        acc1.z = fmaf(a, c1.z, acc1.z); acc1.w = fmaf(a, c1.w, acc1.w);
        acc2.x = fmaf(a, c2.x, acc2.x); acc2.y = fmaf(a, c2.y, acc2.y);
        acc2.z = fmaf(a, c2.z, acc2.z); acc2.w = fmaf(a, c2.w, acc2.w);
        node = 2 * node + 1 + ((bits >> lvl) & 1);
    }

    float4* __restrict__ of4 = (float4*)out;
    const int ob = b * FFF_ROWF4 + lane;
    of4[ob]       = acc0;
    of4[ob + 64]  = acc1;
    of4[ob + 128] = acc2;
}

extern "C" void kernel_launch(void* const* d_in, const int* in_sizes, int n_in,
                              void* d_out, int out_size, void* d_ws, size_t ws_size,
                              hipStream_t stream) {
    const float* x   = (const float*)d_in[0];
    const float* w1s = (const float*)d_in[1];
    const float* w2s = (const float*)d_in[2];
    float* out = (float*)d_out;

    const int B = out_size / FFF_D;                        // 16384
    const int blocks = (B + WAVES_PER_BLOCK - 1) / WAVES_PER_BLOCK;

    const size_t n_elems = (size_t)FFF_NODES * FFF_D;      // 3,144,960
    const size_t needed = 2 * n_elems * sizeof(unsigned short);

    if (ws_size >= needed) {
        unsigned short* w1b = (unsigned short*)d_ws;
        unsigned short* w2b = w1b + n_elems;
        const int nf4 = (int)(n_elems / 4);                // 786,240
        const int cblocks = (2 * nf4 + 1023) / 1024;
        fff_convert_kernel<<<cblocks, 1024, 0, stream>>>(
            (const float4*)w1s, (const float4*)w2s,
            (ushort4*)w1b, (ushort4*)w2b, nf4);
        fff_sparse_kernel_bf16<<<blocks, WAVES_PER_BLOCK * 64, 0, stream>>>(
            x, w1s, w1b, w2b, out, B);
    } else {
        fff_sparse_kernel_f32<<<blocks, WAVES_PER_BLOCK * 64, 0, stream>>>(
            x, w1s, w2s, out, B);
    }
}

// Round 16
// 65.639 us; speedup vs baseline: 1.2967x; 1.2967x over previous
//
#include <hip/hip_runtime.h>
#include <math.h>

// FFF sparse tree forward. B=16384, D_IN=D_OUT=768, DEPTH=11, n_nodes=4095.
//
// Model (R10-R14): time ~= gathered bytes through the per-CU vector path
// (~18 B/cy/CU effective). Requests (R13), occupancy (R11), chain compute
// (R9), phase merge (R14: SPILLS) all null/negative. R15 moves the hot
// top-of-tree rows to the LDS pipe: levels 0-4 of W1 (31 rows) + levels 0-3
// of w2 (15 rows) = 46 rows x 1536 B = 69 KB staged per block; 16 samples
// amortize. Removes 9 of 24 gathered rows/sample from the L1 path (-37% of
// weight bytes); LDS reads are conflict-free contiguous-16B; staging reads
// are sequential and L2-hot.
//
// Phase-split retained (R14: merging spills). bf16 weights (R12) with
// packed 2-request lane map (R13). Sign exact vs f64 reference via
// |p|<0.03 -> f64 recompute from original f32 w1s.
// Tripwires: VGPR <= 72, WRITE_SIZE(main) == 49152 KB, bank conflicts ~0.

#define FFF_LVLS 12        // depth+1
#define FFF_D 768
#define FFF_ROWF4 192      // float4 per 768-f32 row
#define FFF_NODES 4095
#define WAVES_PER_BLOCK 16
#define NTOP_W1 31         // W1 nodes 0..30  (levels 0-4)
#define NTOP_W2 15         // w2 nodes 0..14  (levels 0-3)

typedef unsigned short u16x8 __attribute__((ext_vector_type(8)));
typedef unsigned short u16x4 __attribute__((ext_vector_type(4)));

__device__ __forceinline__ float gelu_exact(float v) {
    return 0.5f * v * (1.0f + erff(v * 0.70710678118654752440f));
}

__device__ __forceinline__ unsigned short f32_to_bf16_rne(float f) {
    unsigned int u = __builtin_bit_cast(unsigned int, f);
    u += 0x7FFFu + ((u >> 16) & 1u);
    return (unsigned short)(u >> 16);
}
__device__ __forceinline__ float bf(unsigned short h) {
    return __builtin_bit_cast(float, (unsigned int)h << 16);
}

template <int CTRL>
__device__ __forceinline__ float dpp_shr_add(float v) {
    const int t = __builtin_amdgcn_update_dpp(
        0, __builtin_bit_cast(int, v), CTRL, 0xf, 0xf, true);
    return v + __builtin_bit_cast(float, t);
}

// Wave64 sum, pure VALU; lanes 15/31/47/63 hold row totals after 4 steps.
__device__ __forceinline__ float wave_allsum_f32(float v) {
    v = dpp_shr_add<0x111>(v);   // row_shr:1
    v = dpp_shr_add<0x112>(v);   // row_shr:2
    v = dpp_shr_add<0x114>(v);   // row_shr:4
    v = dpp_shr_add<0x118>(v);   // row_shr:8
    const int i15 = __builtin_amdgcn_readlane(__builtin_bit_cast(int, v), 15);
    const int i31 = __builtin_amdgcn_readlane(__builtin_bit_cast(int, v), 31);
    const int i47 = __builtin_amdgcn_readlane(__builtin_bit_cast(int, v), 47);
    const int i63 = __builtin_amdgcn_readlane(__builtin_bit_cast(int, v), 63);
    return (__builtin_bit_cast(float, i15) + __builtin_bit_cast(float, i31))
         + (__builtin_bit_cast(float, i47) + __builtin_bit_cast(float, i63));
}

// f32 -> bf16 staging of W1 and w2 (runs each call; deterministic).
__global__ void __launch_bounds__(1024) fff_convert_kernel(
    const float4* __restrict__ w1, const float4* __restrict__ w2,
    ushort4* __restrict__ o1, ushort4* __restrict__ o2, int nf4)
{
    int i = blockIdx.x * blockDim.x + threadIdx.x;
    if (i < nf4) {
        const float4 v = w1[i];
        ushort4 h;
        h.x = f32_to_bf16_rne(v.x); h.y = f32_to_bf16_rne(v.y);
        h.z = f32_to_bf16_rne(v.z); h.w = f32_to_bf16_rne(v.w);
        o1[i] = h;
    } else if (i < 2 * nf4) {
        const int j = i - nf4;
        const float4 v = w2[j];
        ushort4 h;
        h.x = f32_to_bf16_rne(v.x); h.y = f32_to_bf16_rne(v.y);
        h.z = f32_to_bf16_rne(v.z); h.w = f32_to_bf16_rne(v.w);
        o2[j] = h;
    }
}

__global__ void __launch_bounds__(1024) fff_sparse_kernel_bf16(
    const float* __restrict__ x,
    const float* __restrict__ w1s,              // f32, sign-fallback only
    const unsigned short* __restrict__ w1b,     // bf16, 768 per row
    const unsigned short* __restrict__ w2b,
    float* __restrict__ out,
    int B)
{
    // LDS: W1 nodes 0..30 then w2 nodes 0..14; 46 rows x 768 bf16 = 69 KB.
    __shared__ unsigned short lds_w[(NTOP_W1 + NTOP_W2) * FFF_D];

    // Cooperative staging (sequential, L2-hot; 4416 uint4 total).
    {
        uint4* __restrict__ ldsv = (uint4*)lds_w;
        const uint4* __restrict__ s1 = (const uint4*)w1b;   // first 2976
        const uint4* __restrict__ s2 = (const uint4*)w2b;   // first 1440
        const int n1 = NTOP_W1 * FFF_D / 8;                 // 2976
        const int nt = (NTOP_W1 + NTOP_W2) * FFF_D / 8;     // 4416
        for (int i = threadIdx.x; i < nt; i += 1024)
            ldsv[i] = (i < n1) ? s1[i] : s2[i - n1];
    }
    __syncthreads();

    const int wave = threadIdx.x >> 6;
    const int lane = threadIdx.x & 63;
    const int b = blockIdx.x * WAVES_PER_BLOCK + wave;
    if (b >= B) return;

    const unsigned short* __restrict__ lds_w1 = lds_w;
    const unsigned short* __restrict__ lds_w2 = lds_w + NTOP_W1 * FFF_D;

    const float4* __restrict__ xf4 = (const float4*)(x) + (size_t)b * FFF_ROWF4;

    // Packed lane<->dim map: lane l owns dims 8l..8l+7 and 512+4l..515+4l.
    const float4 xA0 = xf4[2 * lane];
    const float4 xA1 = xf4[2 * lane + 1];
    const float4 xB  = xf4[128 + lane];

    // ---- Phase 1: tree walk. Levels 0-4 W1 from LDS; 5-11 from global.
    float acts[FFF_LVLS];
    int bits = 0;
    int node = 0;

#pragma unroll
    for (int lvl = 0; lvl < FFF_LVLS; ++lvl) {
        u16x8 hA;
        u16x4 hB;
        if (lvl <= 4) {
            const unsigned short* row = lds_w1 + node * FFF_D;
            hA = ((const u16x8*)row)[lane];
            hB = ((const u16x4*)(row + 512))[lane];
        } else {
            const unsigned short* row = w1b + (size_t)node * FFF_D;
            hA = ((const u16x8*)row)[lane];
            hB = ((const u16x4*)(row + 512))[lane];
        }

        float q0 = xA0.x * bf(hA[0]);
        float q1 = xA0.y * bf(hA[1]);
        q0 = fmaf(xA0.z, bf(hA[2]), q0);
        q1 = fmaf(xA0.w, bf(hA[3]), q1);
        q0 = fmaf(xA1.x, bf(hA[4]), q0);
        q1 = fmaf(xA1.y, bf(hA[5]), q1);
        q0 = fmaf(xA1.z, bf(hA[6]), q0);
        q1 = fmaf(xA1.w, bf(hA[7]), q1);
        q0 = fmaf(xB.x,  bf(hB[0]), q0);
        q1 = fmaf(xB.y,  bf(hB[1]), q1);
        q0 = fmaf(xB.z,  bf(hB[2]), q0);
        q1 = fmaf(xB.w,  bf(hB[3]), q1);

        float p = wave_allsum_f32(q0 + q1);   // wave-uniform

        // Sign-ambiguity fallback (~4% of levels): f64 dot on original f32.
        if (__builtin_expect(fabsf(p) < 0.03f, 0)) {
            const float4* __restrict__ rf = (const float4*)w1s
                                          + (size_t)node * FFF_ROWF4;
            const float4 a0 = rf[2 * lane];
            const float4 a1 = rf[2 * lane + 1];
            const float4 a2 = rf[128 + lane];
            double d0 = (double)xA0.x * (double)a0.x;
            double d1 = (double)xA0.y * (double)a0.y;
            d0 += (double)xA0.z * (double)a0.z;
            d1 += (double)xA0.w * (double)a0.w;
            d0 += (double)xA1.x * (double)a1.x;
            d1 += (double)xA1.y * (double)a1.y;
            d0 += (double)xA1.z * (double)a1.z;
            d1 += (double)xA1.w * (double)a1.w;
            d0 += (double)xB.x  * (double)a2.x;
            d1 += (double)xB.y  * (double)a2.y;
            d0 += (double)xB.z  * (double)a2.z;
            d1 += (double)xB.w  * (double)a2.w;
            double pd = d0 + d1;
#pragma unroll
            for (int m = 32; m > 0; m >>= 1) pd += __shfl_xor(pd, m, 64);
            p = (float)pd;
        }

        acts[lvl] = gelu_exact(p);
        const int s = (p >= 0.0f) ? 1 : 0;
        bits |= s << lvl;
        node = 2 * node + 1 + s;
    }

    // ---- Phase 2: w2 accumulation. Levels 0-3 from LDS; 4-11 global.
    float4 accA0 = make_float4(0.f, 0.f, 0.f, 0.f);
    float4 accA1 = make_float4(0.f, 0.f, 0.f, 0.f);
    float4 accB  = make_float4(0.f, 0.f, 0.f, 0.f);

    node = 0;
#pragma unroll
    for (int lvl = 0; lvl < FFF_LVLS; ++lvl) {
        u16x8 hA;
        u16x4 hB;
        if (lvl <= 3) {
            const unsigned short* row = lds_w2 + node * FFF_D;
            hA = ((const u16x8*)row)[lane];
            hB = ((const u16x4*)(row + 512))[lane];
        } else {
            const unsigned short* row = w2b + (size_t)node * FFF_D;
            hA = ((const u16x8*)row)[lane];
            hB = ((const u16x4*)(row + 512))[lane];
        }
        const float a = acts[lvl];
        accA0.x = fmaf(a, bf(hA[0]), accA0.x);
        accA0.y = fmaf(a, bf(hA[1]), accA0.y);
        accA0.z = fmaf(a, bf(hA[2]), accA0.z);
        accA0.w = fmaf(a, bf(hA[3]), accA0.w);
        accA1.x = fmaf(a, bf(hA[4]), accA1.x);
        accA1.y = fmaf(a, bf(hA[5]), accA1.y);
        accA1.z = fmaf(a, bf(hA[6]), accA1.z);
        accA1.w = fmaf(a, bf(hA[7]), accA1.w);
        accB.x  = fmaf(a, bf(hB[0]), accB.x);
        accB.y  = fmaf(a, bf(hB[1]), accB.y);
        accB.z  = fmaf(a, bf(hB[2]), accB.z);
        accB.w  = fmaf(a, bf(hB[3]), accB.w);
        node = 2 * node + 1 + ((bits >> lvl) & 1);
    }

    float4* __restrict__ of4 = (float4*)(out) + (size_t)b * FFF_ROWF4;
    of4[2 * lane]     = accA0;
    of4[2 * lane + 1] = accA1;
    of4[128 + lane]   = accB;
}

// Fallback (ws too small): proven R11 all-f32 kernel.
__global__ void __launch_bounds__(1024) fff_sparse_kernel_f32(
    const float* __restrict__ x,
    const float* __restrict__ w1s,
    const float* __restrict__ w2s,
    float* __restrict__ out,
    int B)
{
    const int wave = threadIdx.x >> 6;
    const int lane = threadIdx.x & 63;
    const int b = blockIdx.x * WAVES_PER_BLOCK + wave;
    if (b >= B) return;

    const float4* __restrict__ xf4  = (const float4*)x;
    const float4* __restrict__ w1f4 = (const float4*)w1s;
    const float4* __restrict__ w2f4 = (const float4*)w2s;

    const int xb = b * FFF_ROWF4 + lane;
    const float4 xv0 = xf4[xb];
    const float4 xv1 = xf4[xb + 64];
    const float4 xv2 = xf4[xb + 128];

    float acts[FFF_LVLS];
    int bits = 0;
    int node = 0;

#pragma unroll
    for (int lvl = 0; lvl < FFF_LVLS; ++lvl) {
        const int r = node * FFF_ROWF4 + lane;
        const float4 a0 = w1f4[r];
        const float4 a1 = w1f4[r + 64];
        const float4 a2 = w1f4[r + 128];
        float q0 = xv0.x * a0.x;
        float q1 = xv0.y * a0.y;
        q0 = fmaf(xv0.z, a0.z, q0);
        q1 = fmaf(xv0.w, a0.w, q1);
        q0 = fmaf(xv1.x, a1.x, q0);
        q1 = fmaf(xv1.y, a1.y, q1);
        q0 = fmaf(xv1.z, a1.z, q0);
        q1 = fmaf(xv1.w, a1.w, q1);
        q0 = fmaf(xv2.x, a2.x, q0);
        q1 = fmaf(xv2.y, a2.y, q1);
        q0 = fmaf(xv2.z, a2.z, q0);
        q1 = fmaf(xv2.w, a2.w, q1);
        float p = wave_allsum_f32(q0 + q1);
        if (__builtin_expect(fabsf(p) < 1e-4f, 0)) {
            double d0 = (double)xv0.x * (double)a0.x;
            double d1 = (double)xv0.y * (double)a0.y;
            d0 += (double)xv0.z * (double)a0.z;
            d1 += (double)xv0.w * (double)a0.w;
            d0 += (double)xv1.x * (double)a1.x;
            d1 += (double)xv1.y * (double)a1.y;
            d0 += (double)xv1.z * (double)a1.z;
            d1 += (double)xv1.w * (double)a1.w;
            d0 += (double)xv2.x * (double)a2.x;
            d1 += (double)xv2.y * (double)a2.y;
            d0 += (double)xv2.z * (double)a2.z;
            d1 += (double)xv2.w * (double)a2.w;
            double pd = d0 + d1;
#pragma unroll
            for (int m = 32; m > 0; m >>= 1) pd += __shfl_xor(pd, m, 64);
            p = (float)pd;
        }
        acts[lvl] = gelu_exact(p);
        const int s = (p >= 0.0f) ? 1 : 0;
        bits |= s << lvl;
        node = 2 * node + 1 + s;
    }

    float4 acc0 = make_float4(0.f, 0.f, 0.f, 0.f);
    float4 acc1 = make_float4(0.f, 0.f, 0.f, 0.f);
    float4 acc2 = make_float4(0.f, 0.f, 0.f, 0.f);
    node = 0;
#pragma unroll
    for (int lvl = 0; lvl < FFF_LVLS; ++lvl) {
        const int r = node * FFF_ROWF4 + lane;
        const float4 c0 = w2f4[r];
        const float4 c1 = w2f4[r + 64];
        const float4 c2 = w2f4[r + 128];
        const float a = acts[lvl];
        acc0.x = fmaf(a, c0.x, acc0.x); acc0.y = fmaf(a, c0.y, acc0.y);
        acc0.z = fmaf(a, c0.z, acc0.z); acc0.w = fmaf(a, c0.w, acc0.w);
        acc1.x = fmaf(a, c1.x, acc1.x); acc1.y = fmaf(a, c1.y, acc1.y);
        acc1.z = fmaf(a, c1.z, acc1.z); acc1.w = fmaf(a, c1.w, acc1.w);
        acc2.x = fmaf(a, c2.x, acc2.x); acc2.y = fmaf(a, c2.y, acc2.y);
        acc2.z = fmaf(a, c2.z, acc2.z); acc2.w = fmaf(a, c2.w, acc2.w);
        node = 2 * node + 1 + ((bits >> lvl) & 1);
    }

    float4* __restrict__ of4 = (float4*)out;
    const int ob = b * FFF_ROWF4 + lane;
    of4[ob]       = acc0;
    of4[ob + 64]  = acc1;
    of4[ob + 128] = acc2;
}

extern "C" void kernel_launch(void* const* d_in, const int* in_sizes, int n_in,
                              void* d_out, int out_size, void* d_ws, size_t ws_size,
                              hipStream_t stream) {
    const float* x   = (const float*)d_in[0];
    const float* w1s = (const float*)d_in[1];
    const float* w2s = (const float*)d_in[2];
    float* out = (float*)d_out;

    const int B = out_size / FFF_D;                        // 16384
    const int blocks = (B + WAVES_PER_BLOCK - 1) / WAVES_PER_BLOCK;

    const size_t n_elems = (size_t)FFF_NODES * FFF_D;      // 3,144,960
    const size_t needed = 2 * n_elems * sizeof(unsigned short);

    if (ws_size >= needed) {
        unsigned short* w1b = (unsigned short*)d_ws;
        unsigned short* w2b = w1b + n_elems;
        const int nf4 = (int)(n_elems / 4);                // 786,240
        const int cblocks = (2 * nf4 + 1023) / 1024;
        fff_convert_kernel<<<cblocks, 1024, 0, stream>>>(
            (const float4*)w1s, (const float4*)w2s,
            (ushort4*)w1b, (ushort4*)w2b, nf4);
        fff_sparse_kernel_bf16<<<blocks, WAVES_PER_BLOCK * 64, 0, stream>>>(
            x, w1s, w1b, w2b, out, B);
    } else {
        fff_sparse_kernel_f32<<<blocks, WAVES_PER_BLOCK * 64, 0, stream>>>(
            x, w1s, w2s, out, B);
    }
}

// Round 17
// 63.081 us; speedup vs baseline: 1.3492x; 1.0406x over previous
//
#include <hip/hip_runtime.h>
#include <math.h>

// FFF sparse tree forward. B=16384, D_IN=D_OUT=768, DEPTH=11, n_nodes=4095.
//
// Evidence ledger: deep-row gather bytes cost (R10/R12); requests (R13),
// occupancy (R11), top-row bytes (R15) null; phase merge spills (R14).
// Remaining measured consumer: VALU 42% of 61us — bf16->f32 converts double
// the per-element cost. R16: stage weights as F16 (more accurate than bf16
// for |w|<=0.036) and use native f16 VALU:
//   - phase-1 dot: v_dot2_f32_f16 (__builtin_amdgcn_fdot2), 6 ops/row
//   - phase-2 acc: (float)h + fmaf -> v_fma_mix_f32
//   - sign fallback |p|<0.01 (~25 sigma of f16-dot error, ~0.8%/level) ->
//     f64 dot on ORIGINAL f32 w1s (routing exact vs f64 numpy reference).
// Structure otherwise identical to R15 (phase-split, packed 2-req map,
// LDS top-staging, 16-wave blocks).
// Tripwires: VGPR <= 72, WRITE_SIZE(main) == 49152 KB.

#define FFF_LVLS 12        // depth+1
#define FFF_D 768
#define FFF_ROWF4 192      // float4 per 768-f32 row
#define FFF_NODES 4095
#define WAVES_PER_BLOCK 16
#define NTOP_W1 31         // W1 nodes 0..30  (levels 0-4)
#define NTOP_W2 15         // w2 nodes 0..14  (levels 0-3)

typedef _Float16 f16x8 __attribute__((ext_vector_type(8)));
typedef _Float16 f16x4 __attribute__((ext_vector_type(4)));
typedef _Float16 f16x2 __attribute__((ext_vector_type(2)));

__device__ __forceinline__ float gelu_exact(float v) {
    return 0.5f * v * (1.0f + erff(v * 0.70710678118654752440f));
}

// 2-way f16 dot-accumulate: c += a.x*b.x + a.y*b.y (v_dot2_f32_f16).
__device__ __forceinline__ float fdot2(f16x2 a, f16x2 b, float c) {
#if __has_builtin(__builtin_amdgcn_fdot2)
    return __builtin_amdgcn_fdot2(a, b, c, false);
#else
    return c + (float)a.x * (float)b.x + (float)a.y * (float)b.y;
#endif
}

template <int CTRL>
__device__ __forceinline__ float dpp_shr_add(float v) {
    const int t = __builtin_amdgcn_update_dpp(
        0, __builtin_bit_cast(int, v), CTRL, 0xf, 0xf, true);
    return v + __builtin_bit_cast(float, t);
}

// Wave64 sum, pure VALU; lanes 15/31/47/63 hold row totals after 4 steps.
__device__ __forceinline__ float wave_allsum_f32(float v) {
    v = dpp_shr_add<0x111>(v);   // row_shr:1
    v = dpp_shr_add<0x112>(v);   // row_shr:2
    v = dpp_shr_add<0x114>(v);   // row_shr:4
    v = dpp_shr_add<0x118>(v);   // row_shr:8
    const int i15 = __builtin_amdgcn_readlane(__builtin_bit_cast(int, v), 15);
    const int i31 = __builtin_amdgcn_readlane(__builtin_bit_cast(int, v), 31);
    const int i47 = __builtin_amdgcn_readlane(__builtin_bit_cast(int, v), 47);
    const int i63 = __builtin_amdgcn_readlane(__builtin_bit_cast(int, v), 63);
    return (__builtin_bit_cast(float, i15) + __builtin_bit_cast(float, i31))
         + (__builtin_bit_cast(float, i47) + __builtin_bit_cast(float, i63));
}

// f32 -> f16 staging of W1 and w2 (runs each call; deterministic).
__global__ void __launch_bounds__(1024) fff_convert_kernel(
    const float4* __restrict__ w1, const float4* __restrict__ w2,
    f16x4* __restrict__ o1, f16x4* __restrict__ o2, int nf4)
{
    int i = blockIdx.x * blockDim.x + threadIdx.x;
    if (i < nf4) {
        const float4 v = w1[i];
        f16x4 h;
        h.x = (_Float16)v.x; h.y = (_Float16)v.y;
        h.z = (_Float16)v.z; h.w = (_Float16)v.w;
        o1[i] = h;
    } else if (i < 2 * nf4) {
        const int j = i - nf4;
        const float4 v = w2[j];
        f16x4 h;
        h.x = (_Float16)v.x; h.y = (_Float16)v.y;
        h.z = (_Float16)v.z; h.w = (_Float16)v.w;
        o2[j] = h;
    }
}

__global__ void __launch_bounds__(1024) fff_sparse_kernel_f16(
    const float* __restrict__ x,
    const float* __restrict__ w1s,              // f32, sign-fallback only
    const _Float16* __restrict__ w1h,           // f16, 768 per row
    const _Float16* __restrict__ w2h,
    float* __restrict__ out,
    int B)
{
    // LDS: W1 nodes 0..30 then w2 nodes 0..14; 46 rows x 768 f16 = 69 KB.
    __shared__ _Float16 lds_w[(NTOP_W1 + NTOP_W2) * FFF_D];

    // Cooperative staging (sequential, L2-hot).
    {
        uint4* __restrict__ ldsv = (uint4*)lds_w;
        const uint4* __restrict__ s1 = (const uint4*)w1h;
        const uint4* __restrict__ s2 = (const uint4*)w2h;
        const int n1 = NTOP_W1 * FFF_D / 8;                 // 2976
        const int nt = (NTOP_W1 + NTOP_W2) * FFF_D / 8;     // 4416
        for (int i = threadIdx.x; i < nt; i += 1024)
            ldsv[i] = (i < n1) ? s1[i] : s2[i - n1];
    }
    __syncthreads();

    const int wave = threadIdx.x >> 6;
    const int lane = threadIdx.x & 63;
    const int b = blockIdx.x * WAVES_PER_BLOCK + wave;
    if (b >= B) return;

    const _Float16* __restrict__ lds_w1 = lds_w;
    const _Float16* __restrict__ lds_w2 = lds_w + NTOP_W1 * FFF_D;

    const float4* __restrict__ xf4 = (const float4*)(x) + (size_t)b * FFF_ROWF4;

    // Packed lane<->dim map: lane l owns dims 8l..8l+7 and 512+4l..515+4l.
    const float4 xA0 = xf4[2 * lane];
    const float4 xA1 = xf4[2 * lane + 1];
    const float4 xB  = xf4[128 + lane];

    // x in f16 pairs for v_dot2 (f32 copies retained for the fallback).
    f16x2 xh0 = {(_Float16)xA0.x, (_Float16)xA0.y};
    f16x2 xh1 = {(_Float16)xA0.z, (_Float16)xA0.w};
    f16x2 xh2 = {(_Float16)xA1.x, (_Float16)xA1.y};
    f16x2 xh3 = {(_Float16)xA1.z, (_Float16)xA1.w};
    f16x2 xh4 = {(_Float16)xB.x,  (_Float16)xB.y};
    f16x2 xh5 = {(_Float16)xB.z,  (_Float16)xB.w};

    // ---- Phase 1: tree walk. Levels 0-4 W1 from LDS; 5-11 from global.
    float acts[FFF_LVLS];
    int bits = 0;
    int node = 0;

#pragma unroll
    for (int lvl = 0; lvl < FFF_LVLS; ++lvl) {
        f16x8 hA;
        f16x4 hB;
        if (lvl <= 4) {
            const _Float16* row = lds_w1 + node * FFF_D;
            hA = ((const f16x8*)row)[lane];
            hB = ((const f16x4*)(row + 512))[lane];
        } else {
            const _Float16* row = w1h + (size_t)node * FFF_D;
            hA = ((const f16x8*)row)[lane];
            hB = ((const f16x4*)(row + 512))[lane];
        }

        // 6x v_dot2_f32_f16, two chains.
        float q0 = fdot2(xh0, f16x2{hA[0], hA[1]}, 0.f);
        float q1 = fdot2(xh1, f16x2{hA[2], hA[3]}, 0.f);
        q0 = fdot2(xh2, f16x2{hA[4], hA[5]}, q0);
        q1 = fdot2(xh3, f16x2{hA[6], hA[7]}, q1);
        q0 = fdot2(xh4, f16x2{hB[0], hB[1]}, q0);
        q1 = fdot2(xh5, f16x2{hB[2], hB[3]}, q1);

        float p = wave_allsum_f32(q0 + q1);   // wave-uniform

        // Sign-ambiguity fallback (~0.8% of levels at 25 sigma): f64 dot on
        // ORIGINAL f32 weights+x so routing matches the f64 reference.
        if (__builtin_expect(fabsf(p) < 0.01f, 0)) {
            const float4* __restrict__ rf = (const float4*)w1s
                                          + (size_t)node * FFF_ROWF4;
            const float4 a0 = rf[2 * lane];
            const float4 a1 = rf[2 * lane + 1];
            const float4 a2 = rf[128 + lane];
            double d0 = (double)xA0.x * (double)a0.x;
            double d1 = (double)xA0.y * (double)a0.y;
            d0 += (double)xA0.z * (double)a0.z;
            d1 += (double)xA0.w * (double)a0.w;
            d0 += (double)xA1.x * (double)a1.x;
            d1 += (double)xA1.y * (double)a1.y;
            d0 += (double)xA1.z * (double)a1.z;
            d1 += (double)xA1.w * (double)a1.w;
            d0 += (double)xB.x  * (double)a2.x;
            d1 += (double)xB.y  * (double)a2.y;
            d0 += (double)xB.z  * (double)a2.z;
            d1 += (double)xB.w  * (double)a2.w;
            double pd = d0 + d1;
#pragma unroll
            for (int m = 32; m > 0; m >>= 1) pd += __shfl_xor(pd, m, 64);
            p = (float)pd;
        }

        acts[lvl] = gelu_exact(p);
        const int s = (p >= 0.0f) ? 1 : 0;
        bits |= s << lvl;
        node = 2 * node + 1 + s;
    }

    // ---- Phase 2: w2 accumulation. Levels 0-3 from LDS; 4-11 global.
    // (float)h + fmaf -> v_fma_mix_f32 (no separate converts).
    float4 accA0 = make_float4(0.f, 0.f, 0.f, 0.f);
    float4 accA1 = make_float4(0.f, 0.f, 0.f, 0.f);
    float4 accB  = make_float4(0.f, 0.f, 0.f, 0.f);

    node = 0;
#pragma unroll
    for (int lvl = 0; lvl < FFF_LVLS; ++lvl) {
        f16x8 hA;
        f16x4 hB;
        if (lvl <= 3) {
            const _Float16* row = lds_w2 + node * FFF_D;
            hA = ((const f16x8*)row)[lane];
            hB = ((const f16x4*)(row + 512))[lane];
        } else {
            const _Float16* row = w2h + (size_t)node * FFF_D;
            hA = ((const f16x8*)row)[lane];
            hB = ((const f16x4*)(row + 512))[lane];
        }
        const float a = acts[lvl];
        accA0.x = fmaf(a, (float)hA[0], accA0.x);
        accA0.y = fmaf(a, (float)hA[1], accA0.y);
        accA0.z = fmaf(a, (float)hA[2], accA0.z);
        accA0.w = fmaf(a, (float)hA[3], accA0.w);
        accA1.x = fmaf(a, (float)hA[4], accA1.x);
        accA1.y = fmaf(a, (float)hA[5], accA1.y);
        accA1.z = fmaf(a, (float)hA[6], accA1.z);
        accA1.w = fmaf(a, (float)hA[7], accA1.w);
        accB.x  = fmaf(a, (float)hB[0], accB.x);
        accB.y  = fmaf(a, (float)hB[1], accB.y);
        accB.z  = fmaf(a, (float)hB[2], accB.z);
        accB.w  = fmaf(a, (float)hB[3], accB.w);
        node = 2 * node + 1 + ((bits >> lvl) & 1);
    }

    float4* __restrict__ of4 = (float4*)(out) + (size_t)b * FFF_ROWF4;
    of4[2 * lane]     = accA0;
    of4[2 * lane + 1] = accA1;
    of4[128 + lane]   = accB;
}

template <int CTRL>
__device__ __forceinline__ float dpp_shr_add_f(float v);

// Fallback (ws too small): proven R11 all-f32 kernel.
__global__ void __launch_bounds__(1024) fff_sparse_kernel_f32(
    const float* __restrict__ x,
    const float* __restrict__ w1s,
    const float* __restrict__ w2s,
    float* __restrict__ out,
    int B)
{
    const int wave = threadIdx.x >> 6;
    const int lane = threadIdx.x & 63;
    const int b = blockIdx.x * WAVES_PER_BLOCK + wave;
    if (b >= B) return;

    const float4* __restrict__ xf4  = (const float4*)x;
    const float4* __restrict__ w1f4 = (const float4*)w1s;
    const float4* __restrict__ w2f4 = (const float4*)w2s;

    const int xb = b * FFF_ROWF4 + lane;
    const float4 xv0 = xf4[xb];
    const float4 xv1 = xf4[xb + 64];
    const float4 xv2 = xf4[xb + 128];

    float acts[FFF_LVLS];
    int bits = 0;
    int node = 0;

#pragma unroll
    for (int lvl = 0; lvl < FFF_LVLS; ++lvl) {
        const int r = node * FFF_ROWF4 + lane;
        const float4 a0 = w1f4[r];
        const float4 a1 = w1f4[r + 64];
        const float4 a2 = w1f4[r + 128];
        float q0 = xv0.x * a0.x;
        float q1 = xv0.y * a0.y;
        q0 = fmaf(xv0.z, a0.z, q0);
        q1 = fmaf(xv0.w, a0.w, q1);
        q0 = fmaf(xv1.x, a1.x, q0);
        q1 = fmaf(xv1.y, a1.y, q1);
        q0 = fmaf(xv1.z, a1.z, q0);
        q1 = fmaf(xv1.w, a1.w, q1);
        q0 = fmaf(xv2.x, a2.x, q0);
        q1 = fmaf(xv2.y, a2.y, q1);
        q0 = fmaf(xv2.z, a2.z, q0);
        q1 = fmaf(xv2.w, a2.w, q1);
        float p = wave_allsum_f32(q0 + q1);
        if (__builtin_expect(fabsf(p) < 1e-4f, 0)) {
            double d0 = (double)xv0.x * (double)a0.x;
            double d1 = (double)xv0.y * (double)a0.y;
            d0 += (double)xv0.z * (double)a0.z;
            d1 += (double)xv0.w * (double)a0.w;
            d0 += (double)xv1.x * (double)a1.x;
            d1 += (double)xv1.y * (double)a1.y;
            d0 += (double)xv1.z * (double)a1.z;
            d1 += (double)xv1.w * (double)a1.w;
            d0 += (double)xv2.x * (double)a2.x;
            d1 += (double)xv2.y * (double)a2.y;
            d0 += (double)xv2.z * (double)a2.z;
            d1 += (double)xv2.w * (double)a2.w;
            double pd = d0 + d1;
#pragma unroll
            for (int m = 32; m > 0; m >>= 1) pd += __shfl_xor(pd, m, 64);
            p = (float)pd;
        }
        acts[lvl] = gelu_exact(p);
        const int s = (p >= 0.0f) ? 1 : 0;
        bits |= s << lvl;
        node = 2 * node + 1 + s;
    }

    float4 acc0 = make_float4(0.f, 0.f, 0.f, 0.f);
    float4 acc1 = make_float4(0.f, 0.f, 0.f, 0.f);
    float4 acc2 = make_float4(0.f, 0.f, 0.f, 0.f);
    node = 0;
#pragma unroll
    for (int lvl = 0; lvl < FFF_LVLS; ++lvl) {
        const int r = node * FFF_ROWF4 + lane;
        const float4 c0 = w2f4[r];
        const float4 c1 = w2f4[r + 64];
        const float4 c2 = w2f4[r + 128];
        const float a = acts[lvl];
        acc0.x = fmaf(a, c0.x, acc0.x); acc0.y = fmaf(a, c0.y, acc0.y);
        acc0.z = fmaf(a, c0.z, acc0.z); acc0.w = fmaf(a, c0.w, acc0.w);
        acc1.x = fmaf(a, c1.x, acc1.x); acc1.y = fmaf(a, c1.y, acc1.y);
        acc1.z = fmaf(a, c1.z, acc1.z); acc1.w = fmaf(a, c1.w, acc1.w);
        acc2.x = fmaf(a, c2.x, acc2.x); acc2.y = fmaf(a, c2.y, acc2.y);
        acc2.z = fmaf(a, c2.z, acc2.z); acc2.w = fmaf(a, c2.w, acc2.w);
        node = 2 * node + 1 + ((bits >> lvl) & 1);
    }

    float4* __restrict__ of4 = (float4*)out;
    const int ob = b * FFF_ROWF4 + lane;
    of4[ob]       = acc0;
    of4[ob + 64]  = acc1;
    of4[ob + 128] = acc2;
}

extern "C" void kernel_launch(void* const* d_in, const int* in_sizes, int n_in,
                              void* d_out, int out_size, void* d_ws, size_t ws_size,
                              hipStream_t stream) {
    const float* x   = (const float*)d_in[0];
    const float* w1s = (const float*)d_in[1];
    const float* w2s = (const float*)d_in[2];
    float* out = (float*)d_out;

    const int B = out_size / FFF_D;                        // 16384
    const int blocks = (B + WAVES_PER_BLOCK - 1) / WAVES_PER_BLOCK;

    const size_t n_elems = (size_t)FFF_NODES * FFF_D;      // 3,144,960
    const size_t needed = 2 * n_elems * sizeof(_Float16);

    if (ws_size >= needed) {
        _Float16* w1h = (_Float16*)d_ws;
        _Float16* w2h = w1h + n_elems;
        const int nf4 = (int)(n_elems / 4);                // 786,240
        const int cblocks = (2 * nf4 + 1023) / 1024;
        fff_convert_kernel<<<cblocks, 1024, 0, stream>>>(
            (const float4*)w1s, (const float4*)w2s,
            (f16x4*)w1h, (f16x4*)w2h, nf4);
        fff_sparse_kernel_f16<<<blocks, WAVES_PER_BLOCK * 64, 0, stream>>>(
            x, w1s, w1h, w2h, out, B);
    } else {
        fff_sparse_kernel_f32<<<blocks, WAVES_PER_BLOCK * 64, 0, stream>>>(
            x, w1s, w2s, out, B);
    }
}